// Round 1
// baseline (139.779 us; speedup 1.0000x reference)
//
#include <hip/hip_runtime.h>
#include <cstddef>
#include <cstdint>

// InfoNCE loss, B=8192, D=128.
// prep: normalize + bf16 cast + label/conf signs + self-dot
// sim:  dbuf global_load_lds staged bf16 MFMA E.E^T (XOR-swizzled LDS),
//       exp + masked row-sums (tot/diff trick), 256 rows/block
// fin:  per-row loss, mean over valid rows

#define DDIM 128
#define TEMP_SCALE 14.4269504088896340736f  // (1/0.1) * log2(e), folded into A-side

typedef short s8bf __attribute__((ext_vector_type(8)));   // 8 bf16 (4 VGPRs)
typedef float f32x4 __attribute__((ext_vector_type(4)));

typedef __attribute__((address_space(1))) void gas_void;
typedef __attribute__((address_space(3))) void las_void;

__device__ __forceinline__ void gload_lds16(const void* g, void* l) {
    __builtin_amdgcn_global_load_lds((gas_void*)g, (las_void*)l, 16, 0, 0);
}

__device__ __forceinline__ unsigned short f2bf(float f) {
    unsigned int u = __float_as_uint(f);
    u += 0x7fffu + ((u >> 16) & 1u);
    return (unsigned short)(u >> 16);
}
__device__ __forceinline__ float bf2f(unsigned short h) {
    return __uint_as_float(((unsigned int)h) << 16);
}

// ---------------- prep: one wave per row ----------------
__global__ __launch_bounds__(256) void prep_kernel(
    const float* __restrict__ emb, const int* __restrict__ labels,
    const float* __restrict__ conf,
    short* __restrict__ Ea,   // bf16(SCALE * e)  (A-side, pre-scaled)
    short* __restrict__ Eb,   // bf16(e)          (B-side)
    float2* __restrict__ lh,  // (label +-1, sign(conf))
    float* __restrict__ sd,   // scaled self-dot (bf16-rounded), diag of sim*SCALE
    float* __restrict__ pos_sum, float* __restrict__ tot_sum, int B)
{
    int wave = threadIdx.x >> 6;
    int lane = threadIdx.x & 63;
    int row  = blockIdx.x * 4 + wave;
    if (row >= B) return;

    float2 x = ((const float2*)(emb + (size_t)row * DDIM))[lane];
    float ss = x.x * x.x + x.y * x.y;
    #pragma unroll
    for (int m = 32; m; m >>= 1) ss += __shfl_xor(ss, m);
    float inv = 1.0f / fmaxf(sqrtf(ss), 1e-12f);

    float e0 = x.x * inv, e1 = x.y * inv;
    unsigned short ea0 = f2bf(TEMP_SCALE * e0), ea1 = f2bf(TEMP_SCALE * e1);
    unsigned short eb0 = f2bf(e0),              eb1 = f2bf(e1);
    *(ushort2*)(Ea + (size_t)row * DDIM + lane * 2) = make_ushort2(ea0, ea1);
    *(ushort2*)(Eb + (size_t)row * DDIM + lane * 2) = make_ushort2(eb0, eb1);

    float p = bf2f(ea0) * bf2f(eb0) + bf2f(ea1) * bf2f(eb1);
    #pragma unroll
    for (int m = 32; m; m >>= 1) p += __shfl_xor(p, m);

    if (lane == 0) {
        sd[row] = p;
        float l = labels[row] ? 1.0f : -1.0f;
        float c = conf[row];
        float h = (c > 0.0f) ? 1.0f : ((c < 0.0f) ? -1.0f : 0.0f);
        lh[row] = make_float2(l, h);
        pos_sum[row] = 0.0f;
        tot_sum[row] = 0.0f;
    }
}

// ---------------- sim ----------------
// Block = 256 thr = 4 waves, owns 256 rows (wave w -> rows w*64..w*64+63, 4 MFMA row-tiles).
// Cols: 16 y-chunks of 512; within a chunk, 4 groups of 128 cols, double-buffered
// via global_load_lds into XOR-swizzled linear LDS (32 KB per buffer).
// Swizzle: LDS linear offset L holds global byte (L & ~255) | ((L&255) ^ ((L>>8 & 7)<<4));
// reads apply the same XOR -> ds_read_b128 spreads 8x16B slots across banks (2-way, free).
#define GROUPS 4

__global__ __launch_bounds__(256, 2) void sim_kernel(
    const short* __restrict__ Ea, const short* __restrict__ Eb,
    const float2* __restrict__ lh,
    float* __restrict__ pos_sum, float* __restrict__ tot_sum)
{
    __shared__ short tile[2][128 * 128];   // 2 x 32 KB, swizzled, linear for gload_lds

    int lane = threadIdx.x & 63;
    int wave = threadIdx.x >> 6;
    int l16  = lane & 15;
    int quad = lane >> 4;
    int rowBase = blockIdx.x * 256 + wave * 64;   // 4 row-tiles

    // A fragments (loop-invariant): a[t][kc]; A[m=l16][k=quad*8+j], contiguous b128
    s8bf a[4][4];
    #pragma unroll
    for (int t = 0; t < 4; ++t)
        #pragma unroll
        for (int kc = 0; kc < 4; ++kc)
            a[t][kc] = *(const s8bf*)(Ea + (size_t)(rowBase + t * 16 + l16) * DDIM + kc * 32 + quad * 8);

    // C/D layout: col = lane&15, row = quad*4 + reg
    float li[4][4], hi[4][4];
    #pragma unroll
    for (int t = 0; t < 4; ++t)
        #pragma unroll
        for (int r = 0; r < 4; ++r) {
            float2 v = lh[rowBase + t * 16 + quad * 4 + r];
            li[t][r] = v.x; hi[t][r] = v.y;
        }

    float tot[4][4], dif[4][4];
    #pragma unroll
    for (int t = 0; t < 4; ++t)
        #pragma unroll
        for (int r = 0; r < 4; ++r) { tot[t][r] = 0.0f; dif[t][r] = 0.0f; }

    int c0base = blockIdx.y * (GROUPS * 128);

    // prologue: stage group 0 into tile[0]
    {
        const char* gb = (const char*)Eb + (size_t)c0base * 256;
        #pragma unroll
        for (int i = 0; i < 8; ++i) {
            int L  = i * 4096 + wave * 1024 + lane * 16;
            int Ls = L ^ (((L >> 8) & 7) << 4);       // inverse-swizzled source
            gload_lds16(gb + Ls, (char*)&tile[0][0] + (i * 4096 + wave * 1024));
        }
    }
    __syncthreads();

    int cur = 0;
    int swz = (l16 & 7) << 4;
    for (int g = 0; g < GROUPS; ++g) {
        int c0 = c0base + g * 128;

        // per-lane col metadata for this group (issued first: wait entangles less)
        float2 lhjv[8];
        #pragma unroll
        for (int ct = 0; ct < 8; ++ct) lhjv[ct] = lh[c0 + ct * 16 + l16];

        // async-stage next group into the other buffer; latency hides under compute
        if (g + 1 < GROUPS) {
            const char* gb = (const char*)Eb + (size_t)(c0 + 128) * 256;
            #pragma unroll
            for (int i = 0; i < 8; ++i) {
                int L  = i * 4096 + wave * 1024 + lane * 16;
                int Ls = L ^ (((L >> 8) & 7) << 4);
                gload_lds16(gb + Ls, (char*)&tile[cur ^ 1][0] + (i * 4096 + wave * 1024));
            }
        }

        const char* tc = (const char*)&tile[cur][0];
        #pragma unroll
        for (int ct = 0; ct < 8; ++ct) {
            s8bf b[4];
            #pragma unroll
            for (int kc = 0; kc < 4; ++kc)
                b[kc] = *(const s8bf*)(tc + (ct * 16 + l16) * 256 + ((kc * 64 + quad * 16) ^ swz));

            float2 lhj = lhjv[ct];
            #pragma unroll
            for (int t = 0; t < 4; ++t) {
                f32x4 acc;
                #pragma unroll
                for (int r = 0; r < 4; ++r)   // conf mask folded into acc init
                    acc[r] = (hi[t][r] * lhj.y > 0.0f) ? 0.0f : -1e30f;
                #pragma unroll
                for (int kc = 0; kc < 4; ++kc)
                    acc = __builtin_amdgcn_mfma_f32_16x16x32_bf16(a[t][kc], b[kc], acc, 0, 0, 0);
                #pragma unroll
                for (int r = 0; r < 4; ++r) {
                    float e = __builtin_amdgcn_exp2f(acc[r]);
                    tot[t][r] += e;
                    dif[t][r] = fmaf(li[t][r] * lhj.x, e, dif[t][r]);
                }
            }
        }
        __syncthreads();   // drains vmcnt (next buffer staged) + lgkmcnt (our reads)
        cur ^= 1;
    }

    // ---- reduce over the 16 column-lanes, one atomic pair per row ----
    #pragma unroll
    for (int t = 0; t < 4; ++t)
        #pragma unroll
        for (int r = 0; r < 4; ++r) {
            float tv = tot[t][r], dv = dif[t][r];
            #pragma unroll
            for (int m = 1; m < 16; m <<= 1) {
                tv += __shfl_xor(tv, m);
                dv += __shfl_xor(dv, m);
            }
            if (l16 == 0) {
                int row = rowBase + t * 16 + quad * 4 + r;
                // pos (incl. diagonal) = (tot + dif) / 2 since labels are +-1
                atomicAdd(&pos_sum[row], 0.5f * (tv + dv));
                atomicAdd(&tot_sum[row], tv);
            }
        }
}

// ---------------- fin ----------------
__global__ __launch_bounds__(1024) void fin_kernel(
    const float* __restrict__ pos_sum, const float* __restrict__ tot_sum,
    const float* __restrict__ sd, const float2* __restrict__ lh,
    float* __restrict__ out, int B)
{
    __shared__ float ssum[16], scnt[16];
    float sum = 0.0f, cnt = 0.0f;
    for (int i = threadIdx.x; i < B; i += 1024) {
        float posr = pos_sum[i];
        float neg  = tot_sum[i] - posr;   // diagonal cancels
        float diag = (lh[i].y != 0.0f) ? __builtin_amdgcn_exp2f(sd[i]) : 0.0f;
        float pos  = posr - diag;
        if (pos > 0.0f && neg > 0.0f) {
            sum += logf((pos + neg + 1e-8f) / pos);
            cnt += 1.0f;
        }
    }
    #pragma unroll
    for (int m = 32; m; m >>= 1) {
        sum += __shfl_xor(sum, m);
        cnt += __shfl_xor(cnt, m);
    }
    int wave = threadIdx.x >> 6, lane = threadIdx.x & 63;
    if (lane == 0) { ssum[wave] = sum; scnt[wave] = cnt; }
    __syncthreads();
    if (threadIdx.x == 0) {
        float S = 0.0f, C = 0.0f;
        #pragma unroll
        for (int w = 0; w < 16; ++w) { S += ssum[w]; C += scnt[w]; }
        out[0] = (C > 0.0f) ? S / fmaxf(C, 1.0f) : 0.0f;
    }
}

extern "C" void kernel_launch(void* const* d_in, const int* in_sizes, int n_in,
                              void* d_out, int out_size, void* d_ws, size_t ws_size,
                              hipStream_t stream) {
    const float* emb    = (const float*)d_in[0];
    const int*   labels = (const int*)d_in[1];
    const float* conf   = (const float*)d_in[2];
    float* out = (float*)d_out;
    int B = in_sizes[1];   // 8192

    char* ws = (char*)d_ws;
    size_t off = 0;
    short*  Ea  = (short*)(ws + off);  off += (size_t)B * DDIM * 2;
    short*  Eb  = (short*)(ws + off);  off += (size_t)B * DDIM * 2;
    float2* lhp = (float2*)(ws + off); off += (size_t)B * 8;
    float*  sd  = (float*)(ws + off);  off += (size_t)B * 4;
    float*  pos = (float*)(ws + off);  off += (size_t)B * 4;
    float*  tot = (float*)(ws + off);  off += (size_t)B * 4;

    prep_kernel<<<B / 4, 256, 0, stream>>>(emb, labels, conf, Ea, Eb, lhp, sd, pos, tot, B);

    int rowBlocks = B / 256;             // 32
    int colChunks = B / (GROUPS * 128);  // 16 -> 512 blocks = 2/CU (LDS-limited)
    sim_kernel<<<dim3(rowBlocks, colChunks), 256, 0, stream>>>(Ea, Eb, lhp, pos, tot);

    fin_kernel<<<1, 1024, 0, stream>>>(pos, tot, sd, lhp, out, B);
}

// Round 2
// 115.133 us; speedup vs baseline: 1.2141x; 1.2141x over previous
//
#include <hip/hip_runtime.h>
#include <cstddef>

// InfoNCE loss, B=8192, D=128.
// prep: normalize + bf16 cast + label/conf signs + self-dot
// sim:  reg-staged (T14 async-split) bf16 MFMA E.E^T in padded LDS,
//       exp + masked row-sums (tot/diff trick)
// fin:  per-row loss, mean over valid rows

#define DDIM 128
#define TEMP_SCALE 14.4269504088896340736f  // (1/0.1) * log2(e), folded into A-side
#define GROUPS 4                            // 128-col groups per block (y-chunk = 512 cols)

typedef short s8bf __attribute__((ext_vector_type(8)));   // 8 bf16 (4 VGPRs)
typedef float f32x4 __attribute__((ext_vector_type(4)));

__device__ __forceinline__ unsigned short f2bf(float f) {
    unsigned int u = __float_as_uint(f);
    u += 0x7fffu + ((u >> 16) & 1u);
    return (unsigned short)(u >> 16);
}
__device__ __forceinline__ float bf2f(unsigned short h) {
    return __uint_as_float(((unsigned int)h) << 16);
}

// ---------------- prep: one wave per row ----------------
__global__ __launch_bounds__(256) void prep_kernel(
    const float* __restrict__ emb, const int* __restrict__ labels,
    const float* __restrict__ conf,
    short* __restrict__ Ea,   // bf16(SCALE * e)  (A-side, pre-scaled)
    short* __restrict__ Eb,   // bf16(e)          (B-side)
    float2* __restrict__ lh,  // (label +-1, sign(conf))
    float* __restrict__ sd,   // scaled self-dot (bf16-rounded), diag of sim*SCALE
    float* __restrict__ pos_sum, float* __restrict__ tot_sum, int B)
{
    int wave = threadIdx.x >> 6;
    int lane = threadIdx.x & 63;
    int row  = blockIdx.x * 4 + wave;
    if (row >= B) return;

    float2 x = ((const float2*)(emb + (size_t)row * DDIM))[lane];
    float ss = x.x * x.x + x.y * x.y;
    #pragma unroll
    for (int m = 32; m; m >>= 1) ss += __shfl_xor(ss, m);
    float inv = 1.0f / fmaxf(sqrtf(ss), 1e-12f);

    float e0 = x.x * inv, e1 = x.y * inv;
    unsigned short ea0 = f2bf(TEMP_SCALE * e0), ea1 = f2bf(TEMP_SCALE * e1);
    unsigned short eb0 = f2bf(e0),              eb1 = f2bf(e1);
    *(ushort2*)(Ea + (size_t)row * DDIM + lane * 2) = make_ushort2(ea0, ea1);
    *(ushort2*)(Eb + (size_t)row * DDIM + lane * 2) = make_ushort2(eb0, eb1);

    float p = bf2f(ea0) * bf2f(eb0) + bf2f(ea1) * bf2f(eb1);
    #pragma unroll
    for (int m = 32; m; m >>= 1) p += __shfl_xor(p, m);

    if (lane == 0) {
        sd[row] = p;
        float l = labels[row] ? 1.0f : -1.0f;
        float c = conf[row];
        float h = (c > 0.0f) ? 1.0f : ((c < 0.0f) ? -1.0f : 0.0f);
        lh[row] = make_float2(l, h);
        pos_sum[row] = 0.0f;
        tot_sum[row] = 0.0f;
    }
}

// ---------------- sim ----------------
// Block = 256 thr = 4 waves, owns 128 rows (wave w -> rows w*32..w*32+31, 2 MFMA row-tiles).
// Cols: 16 y-chunks of 512; 4 groups of 128 cols per chunk. Single padded LDS buffer,
// T14 async-split staging: group g+1 global->regs issued before computing group g,
// regs->LDS written after the read-done barrier. lh for all 512 cols hoisted once.
#define PADS 136   // shorts per LDS row (272 B): bank stride spreads reads evenly (free)

__global__ __launch_bounds__(256, 4) void sim_kernel(
    const short* __restrict__ Ea, const short* __restrict__ Eb,
    const float2* __restrict__ lh,
    float* __restrict__ pos_sum, float* __restrict__ tot_sum)
{
    __shared__ short tile[128 * PADS];       // 34816 B
    __shared__ float2 lhCol[GROUPS * 128];   // 4 KB: all 512 cols of this y-chunk

    int lane = threadIdx.x & 63;
    int wave = threadIdx.x >> 6;
    int l16  = lane & 15;
    int quad = lane >> 4;
    int rowBase = blockIdx.x * 128 + wave * 32;   // 2 row-tiles: rowBase, rowBase+16

    // A fragments (loop-invariant): A[m=l16][k=quad*8+j], contiguous b128
    s8bf a0[4], a1[4];
    #pragma unroll
    for (int kc = 0; kc < 4; ++kc) {
        a0[kc] = *(const s8bf*)(Ea + (size_t)(rowBase +      l16) * DDIM + kc * 32 + quad * 8);
        a1[kc] = *(const s8bf*)(Ea + (size_t)(rowBase + 16 + l16) * DDIM + kc * 32 + quad * 8);
    }

    // C/D layout: col = lane&15, row = quad*4 + reg.  Conf sign per owned row:
    float hi0[4], hi1[4];
    #pragma unroll
    for (int r = 0; r < 4; ++r) {
        hi0[r] = lh[rowBase +      quad * 4 + r].y;
        hi1[r] = lh[rowBase + 16 + quad * 4 + r].y;
    }

    float tot0[4] = {0,0,0,0}, dif0[4] = {0,0,0,0};
    float tot1[4] = {0,0,0,0}, dif1[4] = {0,0,0,0};

    int c0base = blockIdx.y * (GROUPS * 128);

    // hoist all 512 column lh once (visible after the g=0 barrier below)
    #pragma unroll
    for (int i = 0; i < (GROUPS * 128) / 256; ++i)
        lhCol[i * 256 + threadIdx.x] = lh[c0base + i * 256 + threadIdx.x];

    // prefetch group 0 into regs
    int4 st[8];
    {
        const int4* gsrc = (const int4*)(Eb + (size_t)c0base * DDIM);
        #pragma unroll
        for (int i = 0; i < 8; ++i) st[i] = gsrc[i * 256 + threadIdx.x];
    }

    for (int g = 0; g < GROUPS; ++g) {
        // ---- write staged regs into padded LDS ----
        #pragma unroll
        for (int i = 0; i < 8; ++i) {
            int chunk = i * 256 + threadIdx.x;       // 0..2047 (16B units)
            int row = chunk >> 4, off = chunk & 15;
            *(int4*)(tile + row * PADS + off * 8) = st[i];
        }
        __syncthreads();   // staged tile (and, at g=0, lhCol) visible

        // ---- issue next group's loads now; latency hides under compute ----
        if (g + 1 < GROUPS) {
            const int4* gsrc = (const int4*)(Eb + (size_t)(c0base + (g + 1) * 128) * DDIM);
            #pragma unroll
            for (int i = 0; i < 8; ++i) st[i] = gsrc[i * 256 + threadIdx.x];
        }

        // ---- 8 col-tiles of 16 ----
        #pragma unroll 2
        for (int ct = 0; ct < 8; ++ct) {
            s8bf b[4];
            #pragma unroll
            for (int kc = 0; kc < 4; ++kc)
                b[kc] = *(const s8bf*)(tile + (ct * 16 + l16) * PADS + kc * 32 + quad * 8);

            float2 lhj = lhCol[g * 128 + ct * 16 + l16];

            f32x4 acc0, acc1;
            #pragma unroll
            for (int r = 0; r < 4; ++r) {   // conf mask folded into acc init
                acc0[r] = (hi0[r] * lhj.y > 0.0f) ? 0.0f : -1e30f;
                acc1[r] = (hi1[r] * lhj.y > 0.0f) ? 0.0f : -1e30f;
            }
            #pragma unroll
            for (int kc = 0; kc < 4; ++kc) {
                acc0 = __builtin_amdgcn_mfma_f32_16x16x32_bf16(a0[kc], b[kc], acc0, 0, 0, 0);
                acc1 = __builtin_amdgcn_mfma_f32_16x16x32_bf16(a1[kc], b[kc], acc1, 0, 0, 0);
            }
            #pragma unroll
            for (int r = 0; r < 4; ++r) {
                float e0 = __builtin_amdgcn_exp2f(acc0[r]);
                tot0[r] += e0;
                dif0[r] = fmaf(lhj.x, e0, dif0[r]);   // row-label multiply deferred

                float e1 = __builtin_amdgcn_exp2f(acc1[r]);
                tot1[r] += e1;
                dif1[r] = fmaf(lhj.x, e1, dif1[r]);
            }
        }
        __syncthreads();   // all waves done reading tile before next overwrite
    }

    // ---- reduce over the 16 column-lanes, one atomic pair per row ----
    #pragma unroll
    for (int r = 0; r < 4; ++r) {
        float t0 = tot0[r], d0 = dif0[r], t1 = tot1[r], d1 = dif1[r];
        #pragma unroll
        for (int m = 1; m < 16; m <<= 1) {
            t0 += __shfl_xor(t0, m); d0 += __shfl_xor(d0, m);
            t1 += __shfl_xor(t1, m); d1 += __shfl_xor(d1, m);
        }
        if (l16 == 0) {
            int row0 = rowBase +      quad * 4 + r;
            int row1 = rowBase + 16 + quad * 4 + r;
            float li0 = lh[row0].x, li1 = lh[row1].x;
            // pos (incl. diagonal) = (tot + li*dif_raw) / 2 since labels are +-1
            atomicAdd(&pos_sum[row0], 0.5f * (t0 + li0 * d0));
            atomicAdd(&tot_sum[row0], t0);
            atomicAdd(&pos_sum[row1], 0.5f * (t1 + li1 * d1));
            atomicAdd(&tot_sum[row1], t1);
        }
    }
}

// ---------------- fin ----------------
__global__ __launch_bounds__(1024) void fin_kernel(
    const float* __restrict__ pos_sum, const float* __restrict__ tot_sum,
    const float* __restrict__ sd, const float2* __restrict__ lh,
    float* __restrict__ out, int B)
{
    __shared__ float ssum[16], scnt[16];
    float sum = 0.0f, cnt = 0.0f;
    for (int i = threadIdx.x; i < B; i += 1024) {
        float posr = pos_sum[i];
        float neg  = tot_sum[i] - posr;   // diagonal cancels
        float diag = (lh[i].y != 0.0f) ? __builtin_amdgcn_exp2f(sd[i]) : 0.0f;
        float pos  = posr - diag;
        if (pos > 0.0f && neg > 0.0f) {
            sum += logf((pos + neg + 1e-8f) / pos);
            cnt += 1.0f;
        }
    }
    #pragma unroll
    for (int m = 32; m; m >>= 1) {
        sum += __shfl_xor(sum, m);
        cnt += __shfl_xor(cnt, m);
    }
    int wave = threadIdx.x >> 6, lane = threadIdx.x & 63;
    if (lane == 0) { ssum[wave] = sum; scnt[wave] = cnt; }
    __syncthreads();
    if (threadIdx.x == 0) {
        float S = 0.0f, C = 0.0f;
        #pragma unroll
        for (int w = 0; w < 16; ++w) { S += ssum[w]; C += scnt[w]; }
        out[0] = (C > 0.0f) ? S / fmaxf(C, 1.0f) : 0.0f;
    }
}

extern "C" void kernel_launch(void* const* d_in, const int* in_sizes, int n_in,
                              void* d_out, int out_size, void* d_ws, size_t ws_size,
                              hipStream_t stream) {
    const float* emb    = (const float*)d_in[0];
    const int*   labels = (const int*)d_in[1];
    const float* conf   = (const float*)d_in[2];
    float* out = (float*)d_out;
    int B = in_sizes[1];   // 8192

    char* ws = (char*)d_ws;
    size_t off = 0;
    short*  Ea  = (short*)(ws + off);  off += (size_t)B * DDIM * 2;
    short*  Eb  = (short*)(ws + off);  off += (size_t)B * DDIM * 2;
    float2* lhp = (float2*)(ws + off); off += (size_t)B * 8;
    float*  sd  = (float*)(ws + off);  off += (size_t)B * 4;
    float*  pos = (float*)(ws + off);  off += (size_t)B * 4;
    float*  tot = (float*)(ws + off);  off += (size_t)B * 4;

    prep_kernel<<<B / 4, 256, 0, stream>>>(emb, labels, conf, Ea, Eb, lhp, sd, pos, tot, B);

    int rowBlocks = B / 128;             // 64
    int colChunks = B / (GROUPS * 128);  // 16 -> 1024 blocks = 4 blocks/CU
    sim_kernel<<<dim3(rowBlocks, colChunks), 256, 0, stream>>>(Ea, Eb, lhp, pos, tot);

    fin_kernel<<<1, 1024, 0, stream>>>(pos, tot, sd, lhp, out, B);
}

// Round 3
// 110.316 us; speedup vs baseline: 1.2671x; 1.0437x over previous
//
#include <hip/hip_runtime.h>
#include <cstddef>

// InfoNCE loss, B=8192, D=128.
// prep: normalize + bf16 cast + label/conf signs + self-dot
// sim:  reg-staged (T14 async-split) bf16 MFMA E.E^T in padded LDS,
//       exp + masked row-sums (tot/diff trick). All hot-loop state in named
//       scalars; launch_bounds(256,3) so nothing spills (round-2 lesson:
//       the 128-VGPR cap scratched the staging regs -> 105 MB HBM writes).
// fin:  per-row loss, mean over valid rows

#define DDIM 128
#define TEMP_SCALE 14.4269504088896340736f  // (1/0.1) * log2(e), folded into A-side
#define GROUPS 4                            // 128-col groups per block (y-chunk = 512 cols)

typedef short s8bf __attribute__((ext_vector_type(8)));   // 8 bf16 (4 VGPRs)
typedef float f32x4 __attribute__((ext_vector_type(4)));

__device__ __forceinline__ unsigned short f2bf(float f) {
    unsigned int u = __float_as_uint(f);
    u += 0x7fffu + ((u >> 16) & 1u);
    return (unsigned short)(u >> 16);
}
__device__ __forceinline__ float bf2f(unsigned short h) {
    return __uint_as_float(((unsigned int)h) << 16);
}

// ---------------- prep: one wave per row ----------------
__global__ __launch_bounds__(256) void prep_kernel(
    const float* __restrict__ emb, const int* __restrict__ labels,
    const float* __restrict__ conf,
    short* __restrict__ Ea,   // bf16(SCALE * e)  (A-side, pre-scaled)
    short* __restrict__ Eb,   // bf16(e)          (B-side)
    float2* __restrict__ lh,  // (label +-1, sign(conf))
    float* __restrict__ sd,   // scaled self-dot (bf16-rounded), diag of sim*SCALE
    float* __restrict__ pos_sum, float* __restrict__ tot_sum, int B)
{
    int wave = threadIdx.x >> 6;
    int lane = threadIdx.x & 63;
    int row  = blockIdx.x * 4 + wave;
    if (row >= B) return;

    float2 x = ((const float2*)(emb + (size_t)row * DDIM))[lane];
    float ss = x.x * x.x + x.y * x.y;
    #pragma unroll
    for (int m = 32; m; m >>= 1) ss += __shfl_xor(ss, m);
    float inv = 1.0f / fmaxf(sqrtf(ss), 1e-12f);

    float e0 = x.x * inv, e1 = x.y * inv;
    unsigned short ea0 = f2bf(TEMP_SCALE * e0), ea1 = f2bf(TEMP_SCALE * e1);
    unsigned short eb0 = f2bf(e0),              eb1 = f2bf(e1);
    *(ushort2*)(Ea + (size_t)row * DDIM + lane * 2) = make_ushort2(ea0, ea1);
    *(ushort2*)(Eb + (size_t)row * DDIM + lane * 2) = make_ushort2(eb0, eb1);

    float p = bf2f(ea0) * bf2f(eb0) + bf2f(ea1) * bf2f(eb1);
    #pragma unroll
    for (int m = 32; m; m >>= 1) p += __shfl_xor(p, m);

    if (lane == 0) {
        sd[row] = p;
        float l = labels[row] ? 1.0f : -1.0f;
        float c = conf[row];
        float h = (c > 0.0f) ? 1.0f : ((c < 0.0f) ? -1.0f : 0.0f);
        lh[row] = make_float2(l, h);
        pos_sum[row] = 0.0f;
        tot_sum[row] = 0.0f;
    }
}

// ---------------- sim ----------------
// Block = 256 thr = 4 waves, owns 128 rows (wave w -> rows w*32..w*32+31, 2 MFMA row-tiles).
// Cols: 16 y-chunks of 512; 4 groups of 128 cols per chunk. Single padded LDS buffer,
// T14 async-split staging: group g+1 global->regs issued after the write barrier,
// latency hidden under group g's MFMA+exp. lh for all 512 cols hoisted once.
#define PADS 136   // shorts per LDS row (272 B), keeps 16B alignment for int4 writes

#define MFMA16(A, Bf, C) __builtin_amdgcn_mfma_f32_16x16x32_bf16((A), (Bf), (C), 0, 0, 0)

__global__ __launch_bounds__(256, 3) void sim_kernel(
    const short* __restrict__ Ea, const short* __restrict__ Eb,
    const float2* __restrict__ lh,
    float* __restrict__ pos_sum, float* __restrict__ tot_sum)
{
    __shared__ short tile[128 * PADS];       // 34816 B
    __shared__ float2 lhCol[GROUPS * 128];   // 4 KB: all 512 cols of this y-chunk

    const int lane = threadIdx.x & 63;
    const int wave = threadIdx.x >> 6;
    const int l16  = lane & 15;
    const int quad = lane >> 4;
    const int rowBase = blockIdx.x * 128 + wave * 32;   // 2 row-tiles: rowBase, rowBase+16

    // A fragments (loop-invariant): A[m=l16][k=quad*8+j], contiguous b128. Named scalars.
    const short* pa0 = Ea + (size_t)(rowBase +      l16) * DDIM + quad * 8;
    const short* pa1 = Ea + (size_t)(rowBase + 16 + l16) * DDIM + quad * 8;
    s8bf a0_0 = *(const s8bf*)(pa0 +  0);
    s8bf a0_1 = *(const s8bf*)(pa0 + 32);
    s8bf a0_2 = *(const s8bf*)(pa0 + 64);
    s8bf a0_3 = *(const s8bf*)(pa0 + 96);
    s8bf a1_0 = *(const s8bf*)(pa1 +  0);
    s8bf a1_1 = *(const s8bf*)(pa1 + 32);
    s8bf a1_2 = *(const s8bf*)(pa1 + 64);
    s8bf a1_3 = *(const s8bf*)(pa1 + 96);

    // C/D layout: col = lane&15, row = quad*4 + reg.  Conf sign per owned row:
    const float hi00 = lh[rowBase +      quad * 4 + 0].y;
    const float hi01 = lh[rowBase +      quad * 4 + 1].y;
    const float hi02 = lh[rowBase +      quad * 4 + 2].y;
    const float hi03 = lh[rowBase +      quad * 4 + 3].y;
    const float hi10 = lh[rowBase + 16 + quad * 4 + 0].y;
    const float hi11 = lh[rowBase + 16 + quad * 4 + 1].y;
    const float hi12 = lh[rowBase + 16 + quad * 4 + 2].y;
    const float hi13 = lh[rowBase + 16 + quad * 4 + 3].y;

    float t00 = 0, t01 = 0, t02 = 0, t03 = 0;
    float d00 = 0, d01 = 0, d02 = 0, d03 = 0;
    float t10 = 0, t11 = 0, t12 = 0, t13 = 0;
    float d10 = 0, d11 = 0, d12 = 0, d13 = 0;

    const int c0base = blockIdx.y * (GROUPS * 128);

    // hoist all 512 column lh once (visible after the g=0 barrier below)
    lhCol[threadIdx.x]       = lh[c0base + threadIdx.x];
    lhCol[256 + threadIdx.x] = lh[c0base + 256 + threadIdx.x];

    // staging registers (named; must never spill)
    int4 s0, s1, s2, s3, s4, s5, s6, s7;
    #define LDG(colbase) do { \
        const int4* gsrc = (const int4*)(Eb + (size_t)(colbase) * DDIM); \
        s0 = gsrc[0 * 256 + threadIdx.x]; \
        s1 = gsrc[1 * 256 + threadIdx.x]; \
        s2 = gsrc[2 * 256 + threadIdx.x]; \
        s3 = gsrc[3 * 256 + threadIdx.x]; \
        s4 = gsrc[4 * 256 + threadIdx.x]; \
        s5 = gsrc[5 * 256 + threadIdx.x]; \
        s6 = gsrc[6 * 256 + threadIdx.x]; \
        s7 = gsrc[7 * 256 + threadIdx.x]; \
    } while (0)

    #define WRLDS(i, v) do { \
        int chunk = (i) * 256 + threadIdx.x; \
        *(int4*)(tile + (chunk >> 4) * PADS + (chunk & 15) * 8) = (v); \
    } while (0)

    #define BIAS(h) (((h) * lhj.y > 0.0f) ? 0.0f : -1e30f)

    #define CTSTEP(ct) do { \
        const short* tb = tile + ((ct) * 16 + l16) * PADS + quad * 8; \
        s8bf b0 = *(const s8bf*)(tb +  0); \
        s8bf b1 = *(const s8bf*)(tb + 32); \
        s8bf b2 = *(const s8bf*)(tb + 64); \
        s8bf b3 = *(const s8bf*)(tb + 96); \
        float2 lhj = lhCol[g * 128 + (ct) * 16 + l16]; \
        f32x4 acc0, acc1; \
        acc0[0] = BIAS(hi00); acc0[1] = BIAS(hi01); acc0[2] = BIAS(hi02); acc0[3] = BIAS(hi03); \
        acc1[0] = BIAS(hi10); acc1[1] = BIAS(hi11); acc1[2] = BIAS(hi12); acc1[3] = BIAS(hi13); \
        acc0 = MFMA16(a0_0, b0, acc0); acc0 = MFMA16(a0_1, b1, acc0); \
        acc0 = MFMA16(a0_2, b2, acc0); acc0 = MFMA16(a0_3, b3, acc0); \
        acc1 = MFMA16(a1_0, b0, acc1); acc1 = MFMA16(a1_1, b1, acc1); \
        acc1 = MFMA16(a1_2, b2, acc1); acc1 = MFMA16(a1_3, b3, acc1); \
        float e; \
        e = __builtin_amdgcn_exp2f(acc0[0]); t00 += e; d00 = fmaf(lhj.x, e, d00); \
        e = __builtin_amdgcn_exp2f(acc0[1]); t01 += e; d01 = fmaf(lhj.x, e, d01); \
        e = __builtin_amdgcn_exp2f(acc0[2]); t02 += e; d02 = fmaf(lhj.x, e, d02); \
        e = __builtin_amdgcn_exp2f(acc0[3]); t03 += e; d03 = fmaf(lhj.x, e, d03); \
        e = __builtin_amdgcn_exp2f(acc1[0]); t10 += e; d10 = fmaf(lhj.x, e, d10); \
        e = __builtin_amdgcn_exp2f(acc1[1]); t11 += e; d11 = fmaf(lhj.x, e, d11); \
        e = __builtin_amdgcn_exp2f(acc1[2]); t12 += e; d12 = fmaf(lhj.x, e, d12); \
        e = __builtin_amdgcn_exp2f(acc1[3]); t13 += e; d13 = fmaf(lhj.x, e, d13); \
    } while (0)

    // prefetch group 0 into regs
    LDG(c0base);

    for (int g = 0; g < GROUPS; ++g) {
        // ---- write staged regs into padded LDS ----
        WRLDS(0, s0); WRLDS(1, s1); WRLDS(2, s2); WRLDS(3, s3);
        WRLDS(4, s4); WRLDS(5, s5); WRLDS(6, s6); WRLDS(7, s7);
        __syncthreads();   // staged tile (and, at g=0, lhCol) visible

        // ---- issue next group's loads now; latency hides under compute ----
        if (g + 1 < GROUPS) LDG(c0base + (g + 1) * 128);

        // ---- 8 col-tiles of 16 ----
        CTSTEP(0); CTSTEP(1); CTSTEP(2); CTSTEP(3);
        CTSTEP(4); CTSTEP(5); CTSTEP(6); CTSTEP(7);

        __syncthreads();   // all waves done reading tile before next overwrite
    }

    // ---- reduce over the 16 column-lanes, one atomic pair per row ----
    #define REDUCE(tv_, dv_, rowidx) do { \
        float tv = (tv_), dv = (dv_); \
        tv += __shfl_xor(tv, 1); dv += __shfl_xor(dv, 1); \
        tv += __shfl_xor(tv, 2); dv += __shfl_xor(dv, 2); \
        tv += __shfl_xor(tv, 4); dv += __shfl_xor(dv, 4); \
        tv += __shfl_xor(tv, 8); dv += __shfl_xor(dv, 8); \
        if (l16 == 0) { \
            int row = (rowidx); \
            float li = lh[row].x; \
            atomicAdd(&pos_sum[row], 0.5f * (tv + li * dv)); \
            atomicAdd(&tot_sum[row], tv); \
        } \
    } while (0)

    REDUCE(t00, d00, rowBase +      quad * 4 + 0);
    REDUCE(t01, d01, rowBase +      quad * 4 + 1);
    REDUCE(t02, d02, rowBase +      quad * 4 + 2);
    REDUCE(t03, d03, rowBase +      quad * 4 + 3);
    REDUCE(t10, d10, rowBase + 16 + quad * 4 + 0);
    REDUCE(t11, d11, rowBase + 16 + quad * 4 + 1);
    REDUCE(t12, d12, rowBase + 16 + quad * 4 + 2);
    REDUCE(t13, d13, rowBase + 16 + quad * 4 + 3);
}

// ---------------- fin ----------------
__global__ __launch_bounds__(1024) void fin_kernel(
    const float* __restrict__ pos_sum, const float* __restrict__ tot_sum,
    const float* __restrict__ sd, const float2* __restrict__ lh,
    float* __restrict__ out, int B)
{
    __shared__ float ssum[16], scnt[16];
    float sum = 0.0f, cnt = 0.0f;
    for (int i = threadIdx.x; i < B; i += 1024) {
        float posr = pos_sum[i];
        float neg  = tot_sum[i] - posr;   // diagonal cancels
        float diag = (lh[i].y != 0.0f) ? __builtin_amdgcn_exp2f(sd[i]) : 0.0f;
        float pos  = posr - diag;
        if (pos > 0.0f && neg > 0.0f) {
            sum += logf((pos + neg + 1e-8f) / pos);
            cnt += 1.0f;
        }
    }
    #pragma unroll
    for (int m = 32; m; m >>= 1) {
        sum += __shfl_xor(sum, m);
        cnt += __shfl_xor(cnt, m);
    }
    int wave = threadIdx.x >> 6, lane = threadIdx.x & 63;
    if (lane == 0) { ssum[wave] = sum; scnt[wave] = cnt; }
    __syncthreads();
    if (threadIdx.x == 0) {
        float S = 0.0f, C = 0.0f;
        #pragma unroll
        for (int w = 0; w < 16; ++w) { S += ssum[w]; C += scnt[w]; }
        out[0] = (C > 0.0f) ? S / fmaxf(C, 1.0f) : 0.0f;
    }
}

extern "C" void kernel_launch(void* const* d_in, const int* in_sizes, int n_in,
                              void* d_out, int out_size, void* d_ws, size_t ws_size,
                              hipStream_t stream) {
    const float* emb    = (const float*)d_in[0];
    const int*   labels = (const int*)d_in[1];
    const float* conf   = (const float*)d_in[2];
    float* out = (float*)d_out;
    int B = in_sizes[1];   // 8192

    char* ws = (char*)d_ws;
    size_t off = 0;
    short*  Ea  = (short*)(ws + off);  off += (size_t)B * DDIM * 2;
    short*  Eb  = (short*)(ws + off);  off += (size_t)B * DDIM * 2;
    float2* lhp = (float2*)(ws + off); off += (size_t)B * 8;
    float*  sd  = (float*)(ws + off);  off += (size_t)B * 4;
    float*  pos = (float*)(ws + off);  off += (size_t)B * 4;
    float*  tot = (float*)(ws + off);  off += (size_t)B * 4;

    prep_kernel<<<B / 4, 256, 0, stream>>>(emb, labels, conf, Ea, Eb, lhp, sd, pos, tot, B);

    int rowBlocks = B / 128;             // 64
    int colChunks = B / (GROUPS * 128);  // 16 -> 1024 blocks
    sim_kernel<<<dim3(rowBlocks, colChunks), 256, 0, stream>>>(Ea, Eb, lhp, pos, tot);

    fin_kernel<<<1, 1024, 0, stream>>>(pos, tot, sd, lhp, out, B);
}